// Round 13
// baseline (266.569 us; speedup 1.0000x reference)
//
#include <hip/hip_runtime.h>
#include <hip/hip_bf16.h>

// C[m][o] = sum_i x[m][i] * ternary[o][i] * scales[o*32 + i/128]
// M=8192, N=4096, K=4096. Fused prepass to bf16 (x cvt + W dequant) in d_ws,
// then 256x256 bf16 NT-GEMM, R13: 2-barrier-per-K-tile sections, NO lgkm
// walls — compiler emits fine-grained per-fragment lgkm waits so ds_reads
// stream on the LDS port while the MFMA pipe crunches (m97 behavior), and
// waves skew between barriers. WAR safety via barrier-certified drains:
//   mid-bar: all waves consumed B,A.q0,A.q1 -> B,A.h0 regions re-writable
//   end-bar: all waves consumed A.q2,A.q3  -> A.h1 region re-writable
// Stage ledger (verified, incl. prologue/dup/tail): section s (buf b=s&1):
//   start: A.h1(s+1)->buf(1-b); after mid: B.h0,B.h1,A.h0(s+2)->buf(b);
//   end: vmcnt(6) publishes tile s+1. Prologue 16 loads + vmcnt(8).

#define Msz 8192
#define Nsz 4096
#define Ksz 4096

typedef __attribute__((ext_vector_type(8))) short short8;
typedef __attribute__((ext_vector_type(4))) float f32x4;
typedef __attribute__((ext_vector_type(4))) int int4v;
typedef __attribute__((ext_vector_type(4))) float float4v;
typedef __attribute__((ext_vector_type(8))) unsigned short ushort8;

static __device__ __forceinline__ unsigned short f2bf(float f) {
    unsigned u = __builtin_bit_cast(unsigned, f);
    u += 0x7fffu + ((u >> 16) & 1u);
    return (unsigned short)(u >> 16);
}

// ---------------- fused prepass: blocks [0,2048) cvt x ; [2048,3072) dequant W ----------------
__global__ void prep(const float* __restrict__ x, const int* __restrict__ t,
                     const float* __restrict__ s,
                     unsigned short* __restrict__ ox, unsigned short* __restrict__ ow) {
    if (blockIdx.x < 2048) {
        int i = blockIdx.x * 256 + threadIdx.x;
        for (; i < Msz * Ksz / 8; i += 2048 * 256) {
            const float4v* p = (const float4v*)x + (size_t)i * 2;
            float4v a = p[0], b = p[1];
            ushort8 r;
            r[0] = f2bf(a[0]); r[1] = f2bf(a[1]); r[2] = f2bf(a[2]); r[3] = f2bf(a[3]);
            r[4] = f2bf(b[0]); r[5] = f2bf(b[1]); r[6] = f2bf(b[2]); r[7] = f2bf(b[3]);
            *((ushort8*)ox + i) = r;
        }
    } else {
        int i = (blockIdx.x - 2048) * 256 + threadIdx.x;
        for (; i < Nsz * Ksz / 8; i += 1024 * 256) {
            float sc = s[i >> 4];  // 8-elem chunk stays inside one 128-group
            const int4v* p = (const int4v*)t + (size_t)i * 2;
            int4v a = p[0], b = p[1];
            ushort8 r;
            r[0] = f2bf((float)a[0] * sc); r[1] = f2bf((float)a[1] * sc);
            r[2] = f2bf((float)a[2] * sc); r[3] = f2bf((float)a[3] * sc);
            r[4] = f2bf((float)b[0] * sc); r[5] = f2bf((float)b[1] * sc);
            r[6] = f2bf((float)b[2] * sc); r[7] = f2bf((float)b[3] * sc);
            *((ushort8*)ow + i) = r;
        }
    }
}

// ---------------- main GEMM ----------------
// 8 waves (2M x 4N). Per-wave 8 M-frags at rowTile = q*4 + wr*2 + m; quadrant q
// lies in A-half q>>1 (q0,q1 -> A.h0; q2,q3 -> A.h1). LDS: 2 buf x {A 32K, B 32K},
// 1KiB subtiles (16r x 32k), XOR-swizzled (verified involution).

#define READ_Bv(b) {                                                             \
    _Pragma("unroll") for (int n = 0; n < 4; ++n)                                \
    _Pragma("unroll") for (int ks = 0; ks < 2; ++ks)                             \
      bfr[n][ks] = *(const short8*)(L + (b)*65536 + 32768 + ((((wc)*4+n)*2+ks)<<10) + laneA); }

#define READ_Aq(S, b, q) {                                                       \
    _Pragma("unroll") for (int m = 0; m < 2; ++m)                                \
    _Pragma("unroll") for (int ks = 0; ks < 2; ++ks)                             \
      S[m][ks] = *(const short8*)(L + (b)*65536 + ((((q)*4+(wr)*2+m)*2+ks)<<10) + laneA); }

#define MFMAS_Q(q, AF) {                                                         \
    _Pragma("unroll") for (int m = 0; m < 2; ++m)                                \
    _Pragma("unroll") for (int n = 0; n < 4; ++n) {                              \
      acc[(q)*2+m][n] = __builtin_amdgcn_mfma_f32_16x16x32_bf16(AF[m][0], bfr[n][0], acc[(q)*2+m][n], 0, 0, 0); \
      acc[(q)*2+m][n] = __builtin_amdgcn_mfma_f32_16x16x32_bf16(AF[m][1], bfr[n][1], acc[(q)*2+m][n], 0, 0, 0); } }

// Stage one M-half (128 rows x K=64 = 16KB) at K-tile T into BOFF+MOFF+H*16384.
#define STAGE_H(PM, MOFF, BOFF, T, H) {                                          \
    _Pragma("unroll") for (int j = 0; j < 2; ++j)                                \
      __builtin_amdgcn_global_load_lds(                                          \
        (const __attribute__((address_space(1))) void*)(PM + (size_t)((H)*128 + j*64)*Ksz + (T)*64), \
        (__attribute__((address_space(3))) void*)(L + (BOFF) + (MOFF) + (H)*16384 + j*8192 + dOff), \
        16, 0, 0); }

#define BAR_ONLY                                                                 \
    __builtin_amdgcn_sched_barrier(0);                                           \
    __builtin_amdgcn_s_barrier();                                                \
    __builtin_amdgcn_sched_barrier(0);

#define BAR_V6                                                                   \
    __builtin_amdgcn_sched_barrier(0);                                           \
    asm volatile("s_waitcnt vmcnt(6)" ::: "memory");                             \
    __builtin_amdgcn_s_barrier();                                                \
    __builtin_amdgcn_sched_barrier(0);

// One K-tile section: b = buffer, TA1 = tile for start A.h1 stage (-> buf 1-b),
// TBA = tile for post-mid B+A.h0 stages (-> buf b).
#define SECTION(b, TA1, TBA)                                                     \
    STAGE_H(pAb, 0, (1-(b))*65536, TA1, 1);                                      \
    READ_Bv(b);                                                                  \
    READ_Aq(afA, b, 0);                                                          \
    READ_Aq(afB, b, 1);                                                          \
    __builtin_amdgcn_s_setprio(1);                                               \
    MFMAS_Q(0, afA);                                                             \
    MFMAS_Q(1, afB);                                                             \
    __builtin_amdgcn_s_setprio(0);                                               \
    BAR_ONLY                                                                     \
    STAGE_H(pBb, 32768, (b)*65536, TBA, 0);                                      \
    STAGE_H(pBb, 32768, (b)*65536, TBA, 1);                                      \
    STAGE_H(pAb, 0,     (b)*65536, TBA, 0);                                      \
    READ_Aq(afA, b, 2);                                                          \
    READ_Aq(afB, b, 3);                                                          \
    __builtin_amdgcn_s_setprio(1);                                               \
    MFMAS_Q(2, afA);                                                             \
    MFMAS_Q(3, afB);                                                             \
    __builtin_amdgcn_s_setprio(0);                                               \
    BAR_V6

__global__ __launch_bounds__(512, 2) void gemm_8p(const unsigned short* __restrict__ A,
                                                  const unsigned short* __restrict__ B,
                                                  float* __restrict__ C) {
    __shared__ __align__(16) unsigned char L[131072]; // 128 KiB

    const int tid  = threadIdx.x;
    const int lane = tid & 63;
    const int wid  = tid >> 6;
    const int wr   = wid >> 2;   // 0..1
    const int wc   = wid & 3;    // 0..3
    const int rowBase = blockIdx.y * 256;
    const int colBase = blockIdx.x * 256;

    // reader swizzled per-lane byte offset within a 1KiB subtile
    const int laneA = (((lane & 15) * 64) + ((lane >> 4) * 16)) ^ (((lane >> 3) & 1) << 5);
    // stager inverse-swizzled per-lane source k-offset (verified involution)
    const int kloc = (lane & 1) * 8 + (((lane >> 1) ^ (lane >> 5)) & 1) * 16;
    const int r_st = lane >> 2;
    const int dOff = wid * 1024;

    const unsigned short* pAb = A + (size_t)(rowBase + (wid >> 1) * 16 + r_st) * Ksz + (wid & 1) * 32 + kloc;
    const unsigned short* pBb = B + (size_t)(colBase + (wid >> 1) * 16 + r_st) * Ksz + (wid & 1) * 32 + kloc;

    f32x4 acc[8][4] = {};
    short8 afA[2][2], afB[2][2], bfr[4][2];

    // ---- prologue: t0 all 4 units, then t1 all 4 units (16 loads) ----
    STAGE_H(pBb, 32768, 0,     0, 0);
    STAGE_H(pBb, 32768, 0,     0, 1);
    STAGE_H(pAb, 0,     0,     0, 0);
    STAGE_H(pAb, 0,     0,     0, 1);
    STAGE_H(pBb, 32768, 65536, 1, 0);
    STAGE_H(pBb, 32768, 65536, 1, 1);
    STAGE_H(pAb, 0,     65536, 1, 0);
    STAGE_H(pAb, 0,     65536, 1, 1);
    __builtin_amdgcn_sched_barrier(0);
    asm volatile("s_waitcnt vmcnt(8)" ::: "memory");  // t0 complete; t1 in flight
    __builtin_amdgcn_s_barrier();
    __builtin_amdgcn_sched_barrier(0);

    for (int i = 0; i < 32; ++i) {
        const int t1 = 2 * i + 1;                  // real tile (<=63)
        const int t2 = (i < 31) ? 2 * i + 2 : 62;  // clamp: dead writes into
        const int t3 = (i < 31) ? 2 * i + 3 : 62;  // barrier-certified-free regions

        SECTION(0, t1, t2)   // tile 2i   in buf0 (i=0: A.h1(1) dup = idempotent)
        SECTION(1, t2, t3)   // tile 2i+1 in buf1
    }

    // drain outstanding gload_lds before LDS teardown / endpgm
    asm volatile("s_waitcnt vmcnt(0) lgkmcnt(0)" ::: "memory");

    // epilogue: frag (q,m) at rowTile q*4+wr*2+m; C/D: col=lane&15, row=(lane>>4)*4+j
    const int crl = (lane >> 4) * 4;
    const int ccol0 = colBase + wc * 64 + (lane & 15);
#pragma unroll
    for (int q = 0; q < 4; ++q)
#pragma unroll
        for (int m = 0; m < 2; ++m)
#pragma unroll
            for (int n = 0; n < 4; ++n) {
                const int row0 = rowBase + (q * 4 + wr * 2 + m) * 16 + crl;
                float* cp = C + (size_t)row0 * Nsz + ccol0 + n * 16;
#pragma unroll
                for (int j = 0; j < 4; ++j)
                    cp[(size_t)j * Nsz] = acc[q * 2 + m][n][j];
            }
}

// ---------------- fallback (ws too small): exact fp32, slow but correct ----------------
__global__ void gemm_naive(const float* __restrict__ x, const int* __restrict__ t,
                           const float* __restrict__ s, float* __restrict__ C) {
    size_t o = (size_t)blockIdx.x * blockDim.x + threadIdx.x;
    if (o >= (size_t)Msz * Nsz) return;
    int m = (int)(o / Nsz), n = (int)(o % Nsz);
    float acc = 0.f;
    for (int g = 0; g < Ksz / 128; ++g) {
        float sc = s[n * (Ksz / 128) + g];
        float p = 0.f;
        const float* xp = x + (size_t)m * Ksz + g * 128;
        const int* tp = t + (size_t)n * Ksz + g * 128;
        for (int k = 0; k < 128; ++k) p += xp[k] * (float)tp[k];
        acc += sc * p;
    }
    C[o] = acc;
}

extern "C" void kernel_launch(void* const* d_in, const int* in_sizes, int n_in,
                              void* d_out, int out_size, void* d_ws, size_t ws_size,
                              hipStream_t stream) {
    const float* x      = (const float*)d_in[0];
    const int*   tern   = (const int*)d_in[1];
    const float* scales = (const float*)d_in[2];
    float* out = (float*)d_out;

    const size_t aBytes = (size_t)Msz * Ksz * 2; // 64 MiB
    const size_t bBytes = (size_t)Nsz * Ksz * 2; // 32 MiB

    if (ws_size >= aBytes + bBytes) {
        unsigned short* Abf = (unsigned short*)d_ws;
        unsigned short* Bbf = (unsigned short*)((char*)d_ws + aBytes);
        prep<<<3072, 256, 0, stream>>>(x, tern, scales, Abf, Bbf);
        dim3 grid(Nsz / 256, Msz / 256);
        gemm_8p<<<grid, 512, 0, stream>>>(Abf, Bbf, out);
    } else {
        gemm_naive<<<(int)(((size_t)Msz * Nsz + 255) / 256), 256, 0, stream>>>(x, tern, scales, out);
    }
}